// Round 6
// baseline (222.036 us; speedup 1.0000x reference)
//
#include <hip/hip_runtime.h>
#include <hip/hip_bf16.h>

#define SEQ     2048
#define BATCH   2
#define HEADS   16
#define HD      128
#define SEGL    1024
#define QSCALE  0.08838834764831845f   // 1/sqrt(128)

typedef __attribute__((ext_vector_type(8))) short bf16x8;
typedef __attribute__((ext_vector_type(4))) float f32x4;
typedef unsigned int u32;

__device__ __forceinline__ short f2bf(float f) {
    __hip_bfloat16 h = __float2bfloat16(f);
    return *reinterpret_cast<short*>(&h);
}

__device__ __forceinline__ bf16x8 cvt8(f32x4 x, f32x4 y) {
    bf16x8 t;
    t[0]=f2bf(x[0]); t[1]=f2bf(x[1]); t[2]=f2bf(x[2]); t[3]=f2bf(x[3]);
    t[4]=f2bf(y[0]); t[5]=f2bf(y[1]); t[6]=f2bf(y[2]); t[7]=f2bf(y[3]);
    return t;
}

// ---------------------------------------------------------------------------
// prep: write K and V bf16 in MFMA-FRAGMENT ORDER, 8192 shorts (16KB) per
// (bh, 64-row s-tile) region.
//   K region: idx = (ct*16 + dg)*128 + lo4*8 + e
//     where fragment kf[ct][c] for lane (lo4,hi4) = K[ct*16+lo4][32c+8hi4+e],
//     dg = 4c+hi4.  A wave's read of one fragment = 1KB contiguous.
//   V region: idx = (oct*128 + d)*8 + e   (oct = k-octet 0..7 within tile)
//     fragment vfa[d0] lane (lo4,hi4) = V[k=8hi4+e][d0*16+lo4], vfb: oct=4+hi4.
// ---------------------------------------------------------------------------
__launch_bounds__(256)
__global__ void prep_kernel(const float* __restrict__ K, const float* __restrict__ V,
                            short* __restrict__ Kfr, short* __restrict__ Vfr)
{
    const int t  = threadIdx.x;
    const int sT = blockIdx.x;        // 64-row s tile (0..31, global over both segs)
    const int bh = blockIdx.y;        // b*HEADS+h (0..31)
    const int b  = bh >> 4, h = bh & 15;
    const size_t inBase  = (size_t)sT * 64 * 4096 + (size_t)b * HEADS * HD + (size_t)h * HD;
    const size_t region  = ((size_t)bh * 32 + sT) * 8192;    // shorts (16KB)

    if (blockIdx.z == 0) {
        #pragma unroll
        for (int i = 0; i < 4; ++i) {
            const int idx = i * 256 + t;
            const int s_loc = idx >> 4, dg = idx & 15;       // dg = 4c+hi4
            const int ct = s_loc >> 4, lo4r = s_loc & 15;
            const float* p = K + inBase + (size_t)s_loc * 4096 + dg * 8;
            f32x4 x = *(const f32x4*)p;
            f32x4 y = *(const f32x4*)(p + 4);
            *(bf16x8*)(Kfr + region + (ct * 16 + dg) * 128 + lo4r * 8) = cvt8(x, y);
        }
    } else {
        __shared__ __align__(16) short lds[64][136];
        #pragma unroll
        for (int i = 0; i < 4; ++i) {
            const int idx = i * 256 + t;
            const int s_loc = idx >> 4, dg = idx & 15;
            const float* p = V + inBase + (size_t)s_loc * 4096 + dg * 8;
            f32x4 x = *(const f32x4*)p;
            f32x4 y = *(const f32x4*)(p + 4);
            *(bf16x8*)(&lds[s_loc][dg * 8]) = cvt8(x, y);
        }
        __syncthreads();
        const int dp = t & 63;        // column pair: d = 2dp, 2dp+1
        const int g  = t >> 6;        // k-row group: rows g*16 .. g*16+15 (octets 2g, 2g+1)
        bf16x8 a0, a1, b0_, b1_;
        #pragma unroll
        for (int j = 0; j < 8; ++j) {
            u32 v = *(const u32*)&lds[g * 16 + j][dp * 2];
            a0[j] = (short)(v & 0xffff);
            a1[j] = (short)(v >> 16);
        }
        #pragma unroll
        for (int j = 0; j < 8; ++j) {
            u32 v = *(const u32*)&lds[g * 16 + 8 + j][dp * 2];
            b0_[j] = (short)(v & 0xffff);
            b1_[j] = (short)(v >> 16);
        }
        short* rg = Vfr + region;
        *(bf16x8*)(rg + ((2 * g)     * 128 + 2 * dp)     * 8) = a0;   // oct 2g,   d even
        *(bf16x8*)(rg + ((2 * g + 1) * 128 + 2 * dp)     * 8) = b0_;  // oct 2g+1, d even
        *(bf16x8*)(rg + ((2 * g)     * 128 + 2 * dp + 1) * 8) = a1;   // oct 2g,   d odd
        *(bf16x8*)(rg + ((2 * g + 1) * 128 + 2 * dp + 1) * 8) = b1_;  // oct 2g+1, d odd
    }
}

// ---------------------------------------------------------------------------
// attention: block = 4 independent waves (16 q-rows each) of one (b,seg,h).
// K/V fragments loaded straight from the fragment-ordered global regions:
// coalesced 1KB/instr, identical addresses across the 4 waves (L1 dedup).
// No LDS staging, no barriers. LDS = plds transpose buffer only (9KB).
// ---------------------------------------------------------------------------
__launch_bounds__(256, 3)
__global__ void attn_fwd(const float* __restrict__ Q,
                         const short* __restrict__ Kfr,
                         const short* __restrict__ Vfr,
                         const float* __restrict__ Bias,
                         float* __restrict__ Out)
{
    __shared__ __align__(16) short plds_all[4][16][72];

    const int tid = threadIdx.x;
    const int w   = tid >> 6;
    const int l   = tid & 63;
    const int lo4 = l & 15;
    const int hi4 = l >> 4;

    const int bsh = blockIdx.x & 63;
    const int st  = 15 - (blockIdx.x >> 6);   // 64-row q supertile, longest first
    const int h   = bsh & 15;
    const int seg = (bsh >> 4) & 1;
    const int b   = bsh >> 5;
    const int bh  = b * HEADS + h;

    const int segBase = seg * SEGL;
    const int i0  = st * 64 + w * 16;         // wave's q-row base (segment-local)
    const int njt = st + 1;

    short (*plds)[72] = plds_all[w];

    // ---- Q fragments (fp32, once) ----
    bf16x8 qf[4];
    {
        const float* qp = Q + (size_t)(segBase + i0 + lo4) * 4096
                            + (size_t)b * HEADS * HD + (size_t)h * HD + 8 * hi4;
        #pragma unroll
        for (int c = 0; c < 4; ++c) {
            f32x4 x = *(const f32x4*)(qp + 32 * c);
            f32x4 y = *(const f32x4*)(qp + 32 * c + 4);
            qf[c] = cvt8(x, y);
        }
    }

    f32x4 o[8];
    #pragma unroll
    for (int d = 0; d < 8; ++d) o[d] = (f32x4){0.f, 0.f, 0.f, 0.f};
    float m_run[4] = {-INFINITY, -INFINITY, -INFINITY, -INFINITY};
    float l_run[4] = {0.f, 0.f, 0.f, 0.f};

    const short* kSeg = Kfr + ((size_t)bh * 32 + seg * 16) * 8192;
    const short* vSeg = Vfr + ((size_t)bh * 32 + seg * 16) * 8192;
    const float* bbase = Bias + ((size_t)b * SEQ + segBase) * SEQ + segBase;

    for (int jt = 0; jt < njt; ++jt) {
        const int j0 = jt * 64;
        const short* kReg = kSeg + (size_t)jt * 8192;
        const short* vReg = vSeg + (size_t)jt * 8192;

        // ---- bias loads (issue first, consumed in softmax) ----
        float bv[4][4];
        #pragma unroll
        for (int r = 0; r < 4; ++r) {
            const int qr = i0 + 4 * hi4 + r;
            const float* bp = bbase + (size_t)qr * SEQ + j0;
            #pragma unroll
            for (int ct = 0; ct < 4; ++ct) bv[r][ct] = bp[ct * 16 + lo4];
        }

        // ---- S = Q K^T : four 16x16 tiles; coalesced fragment loads ----
        f32x4 s[4];
        #pragma unroll
        for (int ct = 0; ct < 4; ++ct) s[ct] = (f32x4){0.f, 0.f, 0.f, 0.f};
        #pragma unroll
        for (int ct = 0; ct < 4; ++ct) {
            const short* kp = kReg + ct * 2048 + hi4 * 128 + lo4 * 8;
            bf16x8 kf0 = *(const bf16x8*)(kp);
            bf16x8 kf1 = *(const bf16x8*)(kp + 512);
            bf16x8 kf2 = *(const bf16x8*)(kp + 1024);
            bf16x8 kf3 = *(const bf16x8*)(kp + 1536);
            s[ct] = __builtin_amdgcn_mfma_f32_16x16x32_bf16(qf[0], kf0, s[ct], 0, 0, 0);
            s[ct] = __builtin_amdgcn_mfma_f32_16x16x32_bf16(qf[1], kf1, s[ct], 0, 0, 0);
            s[ct] = __builtin_amdgcn_mfma_f32_16x16x32_bf16(qf[2], kf2, s[ct], 0, 0, 0);
            s[ct] = __builtin_amdgcn_mfma_f32_16x16x32_bf16(qf[3], kf3, s[ct], 0, 0, 0);
        }

        // ---- V fragments (issue early; overlap softmax) ----
        const short* vpa = vReg + hi4 * 1024 + lo4 * 8;
        const short* vpb = vReg + (4 + hi4) * 1024 + lo4 * 8;
        bf16x8 vfa[8], vfb[8];
        #pragma unroll
        for (int d0 = 0; d0 < 8; ++d0) {
            vfa[d0] = *(const bf16x8*)(vpa + d0 * 128);
            vfb[d0] = *(const bf16x8*)(vpb + d0 * 128);
        }

        // ---- scale + bias (+ causal mask on diagonal tile) + online softmax ----
        const bool diag = (jt == njt - 1);
        #pragma unroll
        for (int r = 0; r < 4; ++r) {
            const int qr = i0 + 4 * hi4 + r;
            float v0 = s[0][r] * QSCALE + bv[r][0];
            float v1 = s[1][r] * QSCALE + bv[r][1];
            float v2 = s[2][r] * QSCALE + bv[r][2];
            float v3 = s[3][r] * QSCALE + bv[r][3];
            if (diag) {
                if (j0 + lo4 > qr)      v0 = -INFINITY;
                if (j0 + 16 + lo4 > qr) v1 = -INFINITY;
                if (j0 + 32 + lo4 > qr) v2 = -INFINITY;
                if (j0 + 48 + lo4 > qr) v3 = -INFINITY;
            }
            float mx = fmaxf(fmaxf(v0, v1), fmaxf(v2, v3));
            mx = fmaxf(mx, __shfl_xor(mx, 1));
            mx = fmaxf(mx, __shfl_xor(mx, 2));
            mx = fmaxf(mx, __shfl_xor(mx, 4));
            mx = fmaxf(mx, __shfl_xor(mx, 8));
            const float mnew = fmaxf(m_run[r], mx);
            const float p0 = __expf(v0 - mnew);
            const float p1 = __expf(v1 - mnew);
            const float p2 = __expf(v2 - mnew);
            const float p3 = __expf(v3 - mnew);
            const float sc = __expf(m_run[r] - mnew);
            m_run[r] = mnew;
            float rs = p0 + p1 + p2 + p3;
            rs += __shfl_xor(rs, 1);
            rs += __shfl_xor(rs, 2);
            rs += __shfl_xor(rs, 4);
            rs += __shfl_xor(rs, 8);
            l_run[r] = l_run[r] * sc + rs;
            #pragma unroll
            for (int d = 0; d < 8; ++d) o[d][r] *= sc;

            short* prow = plds[4 * hi4 + r];
            prow[lo4]      = f2bf(p0);
            prow[16 + lo4] = f2bf(p1);
            prow[32 + lo4] = f2bf(p2);
            prow[48 + lo4] = f2bf(p3);
        }

        // wave-private LDS round-trip (C-layout -> A-layout)
        asm volatile("s_waitcnt lgkmcnt(0)" ::: "memory");
        bf16x8 pf0 = *(const bf16x8*)(&plds[lo4][8 * hi4]);
        bf16x8 pf1 = *(const bf16x8*)(&plds[lo4][32 + 8 * hi4]);

        // ---- O += P V ----
        #pragma unroll
        for (int d0 = 0; d0 < 8; ++d0) {
            o[d0] = __builtin_amdgcn_mfma_f32_16x16x32_bf16(pf0, vfa[d0], o[d0], 0, 0, 0);
            o[d0] = __builtin_amdgcn_mfma_f32_16x16x32_bf16(pf1, vfb[d0], o[d0], 0, 0, 0);
        }
    }

    // ---- epilogue ----
    #pragma unroll
    for (int r = 0; r < 4; ++r) {
        const float inv = 1.0f / l_run[r];
        const int srow = segBase + i0 + 4 * hi4 + r;
        float* op = Out + ((size_t)bh * SEQ + (size_t)srow) * HD + lo4;
        #pragma unroll
        for (int d = 0; d < 8; ++d)
            op[d * 16] = o[d][r] * inv;
    }
}

extern "C" void kernel_launch(void* const* d_in, const int* in_sizes, int n_in,
                              void* d_out, int out_size, void* d_ws, size_t ws_size,
                              hipStream_t stream) {
    const float* Q    = (const float*)d_in[0];
    const float* K    = (const float*)d_in[1];
    const float* V    = (const float*)d_in[2];
    const float* Bias = (const float*)d_in[3];
    float* Out = (float*)d_out;

    short* Kfr = (short*)d_ws;                         // 16 MiB
    short* Vfr = (short*)d_ws + (size_t)8388608;       // 16 MiB

    hipLaunchKernelGGL(prep_kernel, dim3(32, 32, 2), dim3(256), 0, stream, K, V, Kfr, Vfr);
    hipLaunchKernelGGL(attn_fwd, dim3(1024), dim3(256), 0, stream, Q, Kfr, Vfr, Bias, Out);
}